// Round 7
// baseline (250.261 us; speedup 1.0000x reference)
//
#include <hip/hip_runtime.h>
#include <hip/hip_bf16.h>

#define B_DIM 32
#define N_IN 1000000
#define N_OUT 500000

typedef float nfloat4 __attribute__((ext_vector_type(4)));

__device__ __forceinline__ unsigned int f32_to_bf16_rne(float f) {
    unsigned int u = __float_as_uint(f);
    unsigned int rounding = 0x7fffu + ((u >> 16) & 1u);
    return (u + rounding) >> 16;   // low 16 bits = bf16
}

// ---------- Kernel 1: register-only transpose+downconvert ----------
// x (B,N_IN) f32 -> xT (N_IN,B) bf16.  No LDS, no barrier.
// Thread (qi,g): loads float4 (4 consecutive i) from 8 consecutive b-rows
// (b = 8g..8g+7), repacks in registers into 4 x 16B chunks (one per row i+r,
// bf16 pairs of b), stores each at full 64B-line granularity.
__global__ __launch_bounds__(256) void transpose_bf16_v2_kernel(
    const float* __restrict__ x, unsigned short* __restrict__ xT)
{
    const int t  = threadIdx.x;
    const int g  = t & 3;        // b-octet 0..3  (b = 8g..8g+7)
    const int qi = t >> 2;       // i-quad within block 0..63
    const size_t i_quad = (size_t)blockIdx.x * 256 + (size_t)qi * 4;
    if (i_quad >= N_IN) return;  // N_IN % 4 == 0, so full quad is in-bounds

    // 8 coalesced 16B loads (per wave-inst: 4 segments x 256B, line-aligned)
    nfloat4 v[8];
#pragma unroll
    for (int j = 0; j < 8; ++j) {
        v[j] = __builtin_nontemporal_load(
            (const nfloat4*)(x + (size_t)(8 * g + j) * N_IN + i_quad));
    }

    // register micro-transpose: row i_quad+r, chunk g = bf16 pairs of b-octet
#pragma unroll
    for (int r = 0; r < 4; ++r) {
        uint4 pk;
        pk.x = f32_to_bf16_rne(v[0][r]) | (f32_to_bf16_rne(v[1][r]) << 16);
        pk.y = f32_to_bf16_rne(v[2][r]) | (f32_to_bf16_rne(v[3][r]) << 16);
        pk.z = f32_to_bf16_rne(v[4][r]) | (f32_to_bf16_rne(v[5][r]) << 16);
        pk.w = f32_to_bf16_rne(v[6][r]) | (f32_to_bf16_rne(v[7][r]) << 16);
        // per wave-inst: 16 quads x contiguous 64B segment -> full lines
        *(uint4*)((char*)xT + (i_quad + r) * 64 + g * 16) = pk;
    }
}

// ---------- Kernel 2: cooperative gather — 4 lanes share one 64B line ----------
__global__ __launch_bounds__(256) void gather_bf16_v2_kernel(
    const unsigned short* __restrict__ xT,  // (N_IN, 32) bf16
    const float* __restrict__ w,            // (N_OUT, 3)
    const int*   __restrict__ idx,          // (N_OUT, 3)
    float* __restrict__ out)                // (B, N_OUT)
{
    const int t = threadIdx.x;
    const int g = t >> 2;                   // group 0..63
    const int l = t & 3;                    // 16B chunk within line
    const int o = blockIdx.x * 64 + g;
    if (o >= N_OUT) return;

    const int base = 3 * o;
    const int   i0 = __builtin_nontemporal_load(idx + base + 0);
    const int   i1 = __builtin_nontemporal_load(idx + base + 1);
    const int   i2 = __builtin_nontemporal_load(idx + base + 2);
    const float w0 = __builtin_nontemporal_load(w + base + 0);
    const float w1 = __builtin_nontemporal_load(w + base + 1);
    const float w2 = __builtin_nontemporal_load(w + base + 2);

    // lane l's 16B chunk of each 64B row: b = 8l .. 8l+7
    const uint4 v0 = *(const uint4*)(xT + (size_t)i0 * B_DIM + l * 8);
    const uint4 v1 = *(const uint4*)(xT + (size_t)i1 * B_DIM + l * 8);
    const uint4 v2 = *(const uint4*)(xT + (size_t)i2 * B_DIM + l * 8);

    float acc[8];
#pragma unroll
    for (int j = 0; j < 8; ++j) acc[j] = 0.0f;

    const unsigned int u0[4] = {v0.x, v0.y, v0.z, v0.w};
    const unsigned int u1[4] = {v1.x, v1.y, v1.z, v1.w};
    const unsigned int u2[4] = {v2.x, v2.y, v2.z, v2.w};
#pragma unroll
    for (int m = 0; m < 4; ++m) {
        float a = acc[2 * m], c = acc[2 * m + 1];
        a = fmaf(w0, __uint_as_float(u0[m] << 16), a);
        c = fmaf(w0, __uint_as_float(u0[m] & 0xffff0000u), c);
        a = fmaf(w1, __uint_as_float(u1[m] << 16), a);
        c = fmaf(w1, __uint_as_float(u1[m] & 0xffff0000u), c);
        a = fmaf(w2, __uint_as_float(u2[m] << 16), a);
        c = fmaf(w2, __uint_as_float(u2[m] & 0xffff0000u), c);
        acc[2 * m] = a; acc[2 * m + 1] = c;
    }

    // lane l owns b = 8l..8l+7; per store inst: 4 segments x 64B, coalesced
    float* obase = out + (size_t)(8 * l) * N_OUT + o;
#pragma unroll
    for (int j = 0; j < 8; ++j) {
        __builtin_nontemporal_store(acc[j], obase + (size_t)j * N_OUT);
    }
}

// ---------- Fallback (ws too small): direct fp32 gather ----------
__global__ __launch_bounds__(256) void direct_kernel(
    const float* __restrict__ x,
    const float* __restrict__ w,
    const int*   __restrict__ idx,
    float* __restrict__ out)
{
    const int o = blockIdx.x * blockDim.x + threadIdx.x;
    if (o >= N_OUT) return;
    const int base = 3 * o;
    const int i0 = idx[base + 0], i1 = idx[base + 1], i2 = idx[base + 2];
    const float w0 = w[base + 0], w1 = w[base + 1], w2 = w[base + 2];
#pragma unroll 4
    for (int b = 0; b < B_DIM; ++b) {
        const float* __restrict__ xr = x + (size_t)b * N_IN;
        float acc = w0 * xr[i0];
        acc = fmaf(w1, xr[i1], acc);
        acc = fmaf(w2, xr[i2], acc);
        out[(size_t)b * N_OUT + o] = acc;
    }
}

extern "C" void kernel_launch(void* const* d_in, const int* in_sizes, int n_in,
                              void* d_out, int out_size, void* d_ws, size_t ws_size,
                              hipStream_t stream) {
    const float* x   = (const float*)d_in[0];
    const float* w   = (const float*)d_in[1];
    const int*   idx = (const int*)d_in[2];
    float* out = (float*)d_out;

    const size_t xt_bytes = (size_t)N_IN * B_DIM * sizeof(unsigned short); // 64 MB

    if (ws_size >= xt_bytes) {
        unsigned short* xT = (unsigned short*)d_ws;
        const int tblocks = (N_IN + 255) / 256;   // 256 i-rows per block
        transpose_bf16_v2_kernel<<<tblocks, 256, 0, stream>>>(x, xT);
        const int gblocks = (N_OUT + 63) / 64;    // 64 o's per block (4 lanes/o)
        gather_bf16_v2_kernel<<<gblocks, 256, 0, stream>>>(xT, w, idx, out);
    } else {
        const int blocks = (N_OUT + 255) / 256;
        direct_kernel<<<blocks, 256, 0, stream>>>(x, w, idx, out);
    }
}